// Round 1
// baseline (411.994 us; speedup 1.0000x reference)
//
#include <hip/hip_runtime.h>
#include <hip/hip_bf16.h>
#include <stdint.h>

#define DIM 768
#define HID 3072
#define NE 8
#define NTOK 4096
#define PADROWS 5120   // padded slot space (per-expert 128-aligned segments)
#define MAXT 40        // max M-tiles: sum ceil(Ne/128) <= 39

// meta (int) layout inside ws
#define M_PO 0         // [9] padded expert offsets
#define M_NTILES 24
#define M_TE 25        // [40] tile expert
#define M_TR 65        // [40] tile row0 (128-aligned)
#define M_TV 105       // [40] tile valid rows
#define M_PERM 256     // [5120] slot -> token
#define XE_OFF (64 * 1024)
#define H_OFF  8126464         // XE_OFF + 5248*768*2

typedef short short8 __attribute__((ext_vector_type(8)));
typedef short short4v __attribute__((ext_vector_type(4)));
typedef float f32x4 __attribute__((ext_vector_type(4)));

__device__ __forceinline__ short f2bf(float f) {
  union { float f; uint32_t u; } in; in.f = f;
  uint32_t u = in.u;
  uint32_t r = (u + 0x7fffu + ((u >> 16) & 1u)) >> 16;
  return (short)r;
}

// ---------------- routing ----------------
__global__ void route_kernel(const int* __restrict__ map, int* __restrict__ meta) {
  __shared__ int scnt[NE];
  __shared__ int scur[NE];
  int t = threadIdx.x;
  if (t < NE) scnt[t] = 0;
  __syncthreads();
  for (int i = t; i < NTOK; i += 256) atomicAdd(&scnt[map[i]], 1);
  __syncthreads();
  if (t == 0) {
    int acc = 0, nt = 0;
    for (int e = 0; e < NE; ++e) {
      meta[M_PO + e] = acc;
      scur[e] = acc;
      int c = scnt[e];
      for (int r = 0; r < c; r += 128) {
        meta[M_TE + nt] = e;
        meta[M_TR + nt] = acc + r;
        meta[M_TV + nt] = (c - r < 128) ? (c - r) : 128;
        ++nt;
      }
      acc += (c + 127) & ~127;
    }
    meta[M_PO + 8] = acc;
    meta[M_NTILES] = nt;
  }
  for (int i = t; i < PADROWS; i += 256) meta[M_PERM + i] = 0;  // safe token for pads
  __syncthreads();
  for (int i = t; i < NTOK; i += 256) {
    int e = map[i];
    int slot = atomicAdd(&scur[e], 1);
    meta[M_PERM + slot] = i;
  }
}

// ------------- gather x -> Xe (bf16, expert-contiguous, pre-swizzled) -------------
__global__ void gather_kernel(const float* __restrict__ x, const int* __restrict__ meta,
                              short* __restrict__ Xe) {
  int id = blockIdx.x * 256 + threadIdx.x;   // 16B-chunk id
  if (id >= PADROWS * 96) return;
  int row = id / 96;
  int sub = id - row * 96;                    // 96 chunks of 8 cols per row
  int tok = meta[M_PERM + row];
  const float* src = x + (size_t)tok * DIM + sub * 8;
  float4 a = *(const float4*)src;
  float4 b = *(const float4*)(src + 4);
  short8 v;
  v[0] = f2bf(a.x); v[1] = f2bf(a.y); v[2] = f2bf(a.z); v[3] = f2bf(a.w);
  v[4] = f2bf(b.x); v[5] = f2bf(b.y); v[6] = f2bf(b.z); v[7] = f2bf(b.w);
  int blk = sub >> 3, s = sub & 7;
  int off = row * (DIM * 2) + blk * 128 + ((s * 16) ^ ((row & 7) << 4));
  *(short8*)((char*)Xe + off) = v;
}

// ---------------- GEMM1: H = silu(Xe Wg + bg) * (Xe Wi + bi) ----------------
__launch_bounds__(256)
__global__ void gemm1_kernel(const short* __restrict__ Xe, const float* __restrict__ Wg,
                             const float* __restrict__ bg, const float* __restrict__ Wi,
                             const float* __restrict__ bi, const int* __restrict__ meta,
                             short* __restrict__ H) {
  int nt = meta[M_NTILES];
  int ty = blockIdx.y;
  if (ty >= nt) return;
  int e = meta[M_TE + ty], row0 = meta[M_TR + ty], rows = meta[M_TV + ty];
  int j0 = blockIdx.x * 64;
  __shared__ short As[128 * 64];   // [128 rows][64 k] bf16, XOR-swizzled rows
  __shared__ short Bt[2][64 * 64]; // per mat: [64 cols][64 k] bf16, XOR-swizzled
  int tid = threadIdx.x;
  int lane = tid & 63, w = tid >> 6;
  int wm = w >> 1, wn = w & 1;          // 2x2 waves, wave tile 64x32
  const float* W0 = Wg + (size_t)e * DIM * HID;
  const float* W1 = Wi + (size_t)e * DIM * HID;
  f32x4 ag[4][2] = {};
  f32x4 av[4][2] = {};
  int kb = tid >> 4, jb = tid & 15;     // B staging: thread owns 4x4 block
  for (int kt = 0; kt < DIM / 64; ++kt) {
    __syncthreads();
    // ---- stage A via global_load_lds (linear dest; Xe pre-swizzled) ----
    #pragma unroll
    for (int q = 0; q < 4; ++q) {
      int rr = (w * 4 + q) * 8 + (lane >> 3);
      const char* src = (const char*)Xe + (size_t)(row0 + rr) * (DIM * 2) + kt * 128 + (lane & 7) * 16;
      __builtin_amdgcn_global_load_lds((const __attribute__((address_space(1))) void*)src,
                                       (__attribute__((address_space(3))) void*)((char*)As + (w * 4 + q) * 1024),
                                       16, 0, 0);
    }
    // ---- stage B: fp32 load, reg 4x4 transpose, bf16 swizzled K-contig ----
    #pragma unroll
    for (int mat = 0; mat < 2; ++mat) {
      const float* Wp = (mat == 0) ? W0 : W1;
      const float* base = Wp + (size_t)(kt * 64 + kb * 4) * HID + j0 + jb * 4;
      float4 r0 = *(const float4*)(base);
      float4 r1 = *(const float4*)(base + HID);
      float4 r2 = *(const float4*)(base + 2 * HID);
      float4 r3 = *(const float4*)(base + 3 * HID);
      char* bt = (char*)&Bt[mat][0];
      int col = jb * 4;
      {
        short4v s; s[0]=f2bf(r0.x); s[1]=f2bf(r1.x); s[2]=f2bf(r2.x); s[3]=f2bf(r3.x);
        int c2 = col + 0; *(short4v*)(bt + c2 * 128 + ((kb * 8) ^ ((c2 & 7) << 4))) = s;
      }
      {
        short4v s; s[0]=f2bf(r0.y); s[1]=f2bf(r1.y); s[2]=f2bf(r2.y); s[3]=f2bf(r3.y);
        int c2 = col + 1; *(short4v*)(bt + c2 * 128 + ((kb * 8) ^ ((c2 & 7) << 4))) = s;
      }
      {
        short4v s; s[0]=f2bf(r0.z); s[1]=f2bf(r1.z); s[2]=f2bf(r2.z); s[3]=f2bf(r3.z);
        int c2 = col + 2; *(short4v*)(bt + c2 * 128 + ((kb * 8) ^ ((c2 & 7) << 4))) = s;
      }
      {
        short4v s; s[0]=f2bf(r0.w); s[1]=f2bf(r1.w); s[2]=f2bf(r2.w); s[3]=f2bf(r3.w);
        int c2 = col + 3; *(short4v*)(bt + c2 * 128 + ((kb * 8) ^ ((c2 & 7) << 4))) = s;
      }
    }
    __syncthreads();
    // ---- compute ----
    #pragma unroll
    for (int kf = 0; kf < 2; ++kf) {
      short8 af[4];
      #pragma unroll
      for (int m = 0; m < 4; ++m) {
        int r = wm * 64 + m * 16 + (lane & 15);
        int coff = (kf * 64 + (lane >> 4) * 16) ^ ((r & 7) << 4);
        af[m] = *(const short8*)((const char*)As + r * 128 + coff);
      }
      #pragma unroll
      for (int n = 0; n < 2; ++n) {
        int c = wn * 32 + n * 16 + (lane & 15);
        int coff = (kf * 64 + (lane >> 4) * 16) ^ ((c & 7) << 4);
        short8 b0 = *(const short8*)((const char*)&Bt[0][0] + c * 128 + coff);
        short8 b1 = *(const short8*)((const char*)&Bt[1][0] + c * 128 + coff);
        #pragma unroll
        for (int m = 0; m < 4; ++m) {
          ag[m][n] = __builtin_amdgcn_mfma_f32_16x16x32_bf16(af[m], b0, ag[m][n], 0, 0, 0);
          av[m][n] = __builtin_amdgcn_mfma_f32_16x16x32_bf16(af[m], b1, av[m][n], 0, 0, 0);
        }
      }
    }
  }
  // ---- epilogue: bias + silu*v, write H (bf16, pre-swizzled) ----
  #pragma unroll
  for (int n = 0; n < 2; ++n) {
    int c = j0 + wn * 32 + n * 16 + (lane & 15);
    float bgv = bg[e * HID + c];
    float biv = bi[e * HID + c];
    #pragma unroll
    for (int m = 0; m < 4; ++m) {
      #pragma unroll
      for (int r = 0; r < 4; ++r) {
        int rl = wm * 64 + m * 16 + (lane >> 4) * 4 + r;
        if (rl < rows) {
          float g = ag[m][n][r] + bgv;
          float v = av[m][n][r] + biv;
          float h = g / (1.f + __expf(-g)) * v;
          int grow = row0 + rl;
          int off = grow * (HID * 2) + (c >> 6) * 128 + ((2 * (c & 63)) ^ ((grow & 7) << 4));
          *(short*)((char*)H + off) = f2bf(h);
        }
      }
    }
  }
}

// ---------------- GEMM2: out[perm] = H Wo + bo ----------------
__launch_bounds__(256)
__global__ void gemm2_kernel(const short* __restrict__ H, const float* __restrict__ Wo,
                             const float* __restrict__ bo, const int* __restrict__ meta,
                             float* __restrict__ out) {
  int nt = meta[M_NTILES];
  int ty = blockIdx.y;
  if (ty >= nt) return;
  int e = meta[M_TE + ty], row0 = meta[M_TR + ty], rows = meta[M_TV + ty];
  int j0 = blockIdx.x * 64;
  __shared__ short As[128 * 64];
  __shared__ short Bt[64 * 64];
  int tid = threadIdx.x;
  int lane = tid & 63, w = tid >> 6;
  int wm = w >> 1, wn = w & 1;
  const float* W2 = Wo + (size_t)e * HID * DIM;
  f32x4 acc[4][2] = {};
  int kb = tid >> 4, jb = tid & 15;
  for (int kt = 0; kt < HID / 64; ++kt) {
    __syncthreads();
    #pragma unroll
    for (int q = 0; q < 4; ++q) {
      int rr = (w * 4 + q) * 8 + (lane >> 3);
      const char* src = (const char*)H + (size_t)(row0 + rr) * (HID * 2) + kt * 128 + (lane & 7) * 16;
      __builtin_amdgcn_global_load_lds((const __attribute__((address_space(1))) void*)src,
                                       (__attribute__((address_space(3))) void*)((char*)As + (w * 4 + q) * 1024),
                                       16, 0, 0);
    }
    {
      const float* base = W2 + (size_t)(kt * 64 + kb * 4) * DIM + j0 + jb * 4;
      float4 r0 = *(const float4*)(base);
      float4 r1 = *(const float4*)(base + DIM);
      float4 r2 = *(const float4*)(base + 2 * DIM);
      float4 r3 = *(const float4*)(base + 3 * DIM);
      char* bt = (char*)&Bt[0];
      int col = jb * 4;
      {
        short4v s; s[0]=f2bf(r0.x); s[1]=f2bf(r1.x); s[2]=f2bf(r2.x); s[3]=f2bf(r3.x);
        int c2 = col + 0; *(short4v*)(bt + c2 * 128 + ((kb * 8) ^ ((c2 & 7) << 4))) = s;
      }
      {
        short4v s; s[0]=f2bf(r0.y); s[1]=f2bf(r1.y); s[2]=f2bf(r2.y); s[3]=f2bf(r3.y);
        int c2 = col + 1; *(short4v*)(bt + c2 * 128 + ((kb * 8) ^ ((c2 & 7) << 4))) = s;
      }
      {
        short4v s; s[0]=f2bf(r0.z); s[1]=f2bf(r1.z); s[2]=f2bf(r2.z); s[3]=f2bf(r3.z);
        int c2 = col + 2; *(short4v*)(bt + c2 * 128 + ((kb * 8) ^ ((c2 & 7) << 4))) = s;
      }
      {
        short4v s; s[0]=f2bf(r0.w); s[1]=f2bf(r1.w); s[2]=f2bf(r2.w); s[3]=f2bf(r3.w);
        int c2 = col + 3; *(short4v*)(bt + c2 * 128 + ((kb * 8) ^ ((c2 & 7) << 4))) = s;
      }
    }
    __syncthreads();
    #pragma unroll
    for (int kf = 0; kf < 2; ++kf) {
      short8 af[4];
      #pragma unroll
      for (int m = 0; m < 4; ++m) {
        int r = wm * 64 + m * 16 + (lane & 15);
        int coff = (kf * 64 + (lane >> 4) * 16) ^ ((r & 7) << 4);
        af[m] = *(const short8*)((const char*)As + r * 128 + coff);
      }
      #pragma unroll
      for (int n = 0; n < 2; ++n) {
        int c = wn * 32 + n * 16 + (lane & 15);
        int coff = (kf * 64 + (lane >> 4) * 16) ^ ((c & 7) << 4);
        short8 b0 = *(const short8*)((const char*)&Bt[0] + c * 128 + coff);
        #pragma unroll
        for (int m = 0; m < 4; ++m) {
          acc[m][n] = __builtin_amdgcn_mfma_f32_16x16x32_bf16(af[m], b0, acc[m][n], 0, 0, 0);
        }
      }
    }
  }
  #pragma unroll
  for (int n = 0; n < 2; ++n) {
    int c = j0 + wn * 32 + n * 16 + (lane & 15);
    float bov = bo[e * DIM + c];
    #pragma unroll
    for (int m = 0; m < 4; ++m) {
      #pragma unroll
      for (int r = 0; r < 4; ++r) {
        int rl = wm * 64 + m * 16 + (lane >> 4) * 4 + r;
        if (rl < rows) {
          int tok = meta[M_PERM + row0 + rl];
          out[(size_t)tok * DIM + c] = acc[m][n][r] + bov;
        }
      }
    }
  }
}

extern "C" void kernel_launch(void* const* d_in, const int* in_sizes, int n_in,
                              void* d_out, int out_size, void* d_ws, size_t ws_size,
                              hipStream_t stream) {
  (void)in_sizes; (void)n_in; (void)out_size; (void)ws_size;
  const float* x   = (const float*)d_in[0];
  const int*   map = (const int*)d_in[1];
  const float* Wg  = (const float*)d_in[2];
  const float* bg  = (const float*)d_in[3];
  const float* Wi  = (const float*)d_in[4];
  const float* bi  = (const float*)d_in[5];
  const float* Wo  = (const float*)d_in[6];
  const float* bo  = (const float*)d_in[7];
  float* out = (float*)d_out;
  int* meta = (int*)d_ws;
  short* Xe = (short*)((char*)d_ws + XE_OFF);
  short* H  = (short*)((char*)d_ws + H_OFF);

  hipLaunchKernelGGL(route_kernel, dim3(1), dim3(256), 0, stream, map, meta);
  hipLaunchKernelGGL(gather_kernel, dim3(PADROWS * 96 / 256), dim3(256), 0, stream, x, meta, Xe);
  hipLaunchKernelGGL(gemm1_kernel, dim3(HID / 64, MAXT), dim3(256), 0, stream,
                     Xe, Wg, bg, Wi, bi, meta, H);
  hipLaunchKernelGGL(gemm2_kernel, dim3(DIM / 64, MAXT), dim3(256), 0, stream,
                     H, Wo, bo, meta, out);
}